// Round 3
// baseline (231.094 us; speedup 1.0000x reference)
//
#include <hip/hip_runtime.h>
#include <hip/hip_cooperative_groups.h>

namespace cg = cooperative_groups;

// Triple softmax along keys == uniform(1/S) to ~1e-7 elementwise, so
//   out[b,s,:] = ((mean_s' v[b,s',:]) @ Wv.T + bv) @ Wo.T + bo
// independent of q, k, Wq, Wk, padding_mask, s. Measured absmax 2.4e-4
// (threshold 2.34e-3) in rounds 1-2.
//
// Round 3: ONE cooperative kernel (rounds 1-2 showed ~2.5us per dispatch
// gap dominating ~10us of actual work). 512 blocks x 256 thr, 4 grid syncs.

#define BATCH 4
#define SEQ 1024
#define DIM 1024
#define D4 256          // float4 per row
#define RC 128          // P1 row-chunks (8 rows each)
#define NBLK 512

// Wave-per-W-row matvec: y[b][n] = bias[n] + sum_k x[b][k]*W[n][k], all 4 b
// per wave (W row read ONCE). 256 active blocks x 4 waves = 1024 rows.
__device__ __forceinline__ void matvec_phase(
    const float4* __restrict__ W4, const float* __restrict__ bias,
    const float4* __restrict__ xin,   // [4][D4] float4
    float* __restrict__ yout,         // [4][DIM] float
    float4* sh, int bid, int tid)
{
#pragma unroll
    for (int k = 0; k < 4; ++k) sh[k * D4 + tid] = xin[k * D4 + tid];
    __syncthreads();
    const int wv = tid >> 6, lane = tid & 63;
    const int n = bid * 4 + wv;
    const float4* wrow = W4 + (size_t)n * D4;
    float a0 = 0.f, a1 = 0.f, a2 = 0.f, a3 = 0.f;
#pragma unroll
    for (int it = 0; it < 4; ++it) {
        const int col = it * 64 + lane;
        const float4 w  = wrow[col];
        const float4 x0 = sh[col];
        const float4 x1 = sh[D4 + col];
        const float4 x2 = sh[2 * D4 + col];
        const float4 x3 = sh[3 * D4 + col];
        a0 += w.x * x0.x + w.y * x0.y + w.z * x0.z + w.w * x0.w;
        a1 += w.x * x1.x + w.y * x1.y + w.z * x1.z + w.w * x1.w;
        a2 += w.x * x2.x + w.y * x2.y + w.z * x2.z + w.w * x2.w;
        a3 += w.x * x3.x + w.y * x3.y + w.z * x3.z + w.w * x3.w;
    }
#pragma unroll
    for (int off = 32; off > 0; off >>= 1) {
        a0 += __shfl_down(a0, off);
        a1 += __shfl_down(a1, off);
        a2 += __shfl_down(a2, off);
        a3 += __shfl_down(a3, off);
    }
    if (lane == 0) {
        const float bb = bias[n];
        yout[0 * DIM + n] = a0 + bb;
        yout[1 * DIM + n] = a1 + bb;
        yout[2 * DIM + n] = a2 + bb;
        yout[3 * DIM + n] = a3 + bb;
    }
}

__global__ void __launch_bounds__(256, 2) mha_fused(
    const float4* __restrict__ v4,
    const float4* __restrict__ Wv4, const float* __restrict__ bv,
    const float4* __restrict__ Wo4, const float* __restrict__ bo,
    float4* __restrict__ out4,
    float4* __restrict__ part,     // [BATCH][RC][D4]  (2 MB)
    float4* __restrict__ vmean,    // [BATCH][D4]
    float* __restrict__ tbuf,      // [BATCH][DIM]
    float* __restrict__ rbuf)      // [BATCH][DIM]
{
    cg::grid_group grid = cg::this_grid();
    __shared__ float4 sh[1024];    // 16 KB, reused across phases
    const int bid = blockIdx.x;
    const int tid = threadIdx.x;

    // ---- P1: partial colsum of v. block = (b, rc of 8 rows); thread = f4 col
    {
        const int b = bid >> 7, rc = bid & (RC - 1);
        const float4* p = v4 + (size_t)(b * SEQ + rc * 8) * D4 + tid;
        float4 s = {0.f, 0.f, 0.f, 0.f};
#pragma unroll
        for (int i = 0; i < 8; ++i) {
            const float4 a = p[i * D4];
            s.x += a.x; s.y += a.y; s.z += a.z; s.w += a.w;
        }
        part[(size_t)(b * RC + rc) * D4 + tid] = s;
    }
    grid.sync();

    // ---- P2: vmean. 16 blocks = (b, col-quarter); thread = (col, pgroup)
    if (bid < 16) {
        const int b = bid >> 2, cq = bid & 3;
        const int cl = tid & 63, g = tid >> 6;
        const int col = cq * 64 + cl;
        const float4* p = part + (size_t)(b * RC + g * 32) * D4 + col;
        float4 s = {0.f, 0.f, 0.f, 0.f};
#pragma unroll
        for (int i = 0; i < 32; ++i) {
            const float4 a = p[i * D4];
            s.x += a.x; s.y += a.y; s.z += a.z; s.w += a.w;
        }
        sh[g * 64 + cl] = s;
        __syncthreads();
        if (g == 0) {
            const float4 q0 = sh[cl], q1 = sh[64 + cl];
            const float4 q2 = sh[128 + cl], q3 = sh[192 + cl];
            const float inv = 1.0f / SEQ;
            float4 m;
            m.x = (q0.x + q1.x + q2.x + q3.x) * inv;
            m.y = (q0.y + q1.y + q2.y + q3.y) * inv;
            m.z = (q0.z + q1.z + q2.z + q3.z) * inv;
            m.w = (q0.w + q1.w + q2.w + q3.w) * inv;
            vmean[b * D4 + col] = m;
        }
    }
    grid.sync();

    // ---- P3: t = vmean @ Wv.T + bv
    if (bid < 256) matvec_phase(Wv4, bv, vmean, tbuf, sh, bid, tid);
    grid.sync();

    // ---- P4: r = t @ Wo.T + bo
    if (bid < 256) matvec_phase(Wo4, bo, (const float4*)tbuf, rbuf, sh, bid, tid);
    grid.sync();

    // ---- P5: broadcast r to out. block = 8 consecutive s-rows (32 KB region)
    {
        const int b = bid >> 7;                       // 128 blocks per batch
        const float4 val = ((const float4*)rbuf)[b * D4 + tid];
        float4* o = out4 + (size_t)bid * 2048 + tid;
#pragma unroll
        for (int k = 0; k < 8; ++k) o[k * D4] = val;
    }
}

extern "C" void kernel_launch(void* const* d_in, const int* in_sizes, int n_in,
                              void* d_out, int out_size, void* d_ws, size_t ws_size,
                              hipStream_t stream) {
    const float4* v4  = (const float4*)d_in[2];
    const float4* Wv4 = (const float4*)d_in[8];
    const float*  bv  = (const float*)d_in[9];
    const float4* Wo4 = (const float4*)d_in[10];
    const float*  bo  = (const float*)d_in[11];
    float4* out4 = (float4*)d_out;

    float* ws = (float*)d_ws;
    float4* part  = (float4*)ws;                         // 524288 floats (2 MB)
    float4* vmean = (float4*)(ws + 524288);              // 4096 floats
    float*  tbuf  = ws + 524288 + 4096;                  // 4096 floats
    float*  rbuf  = tbuf + 4096;                         // 4096 floats

    void* args[] = { &v4, &Wv4, &bv, &Wo4, &bo, &out4, &part, &vmean, &tbuf, &rbuf };
    hipLaunchCooperativeKernel((const void*)mha_fused, dim3(NBLK), dim3(256),
                               args, 0, stream);
}

// Round 4
// 30.573 us; speedup vs baseline: 7.5586x; 7.5586x over previous
//
#include <hip/hip_runtime.h>

// Triple softmax along keys == uniform(1/S) to ~1e-7, so
//   out[b,s,:] = ((mean_s' v[b,s',:]) @ Wv.T + bv) @ Wo.T + bo
// independent of q, k, Wq, Wk, padding_mask, s. Measured absmax 2.4e-4
// (threshold 2.34e-3) rounds 1-3.
//
// Round 4: cooperative grid.sync measured ~50us/sync on gfx950 (round 3:
// 226us kernel, traffic as predicted) -> back to conventional dispatches.
// Minimum barriers for this factorization = 3 -> 4 kernels:
//   K1 partial colsum (float4, 2048 waves)
//   K2 finalize (L2-served redundant part re-read) + t = vmean@Wv.T + bv
//   K3 r = t@Wo.T + bo  (Wo read exactly once; wave = one row, all 4 batches)
//   K4 coalesced broadcast of r to out

#define BATCH 4
#define SEQ 1024
#define DIM 1024
#define D4 256            // float4 per row
#define RCH 128           // K1 row-chunks (8 rows each)

// ---- K1: part[b][rc][:] = sum of 8 rows of v. grid (4,128), 256 thr ----
__global__ void __launch_bounds__(256) k1_colsum(const float4* __restrict__ v4,
                                                 float4* __restrict__ part) {
    const int b = blockIdx.x, rc = blockIdx.y, tid = threadIdx.x;
    const float4* p = v4 + (size_t)(b * SEQ + rc * 8) * D4 + tid;
    float4 s = {0.f, 0.f, 0.f, 0.f};
#pragma unroll
    for (int i = 0; i < 8; ++i) {
        const float4 a = p[i * D4];
        s.x += a.x; s.y += a.y; s.z += a.z; s.w += a.w;
    }
    part[(size_t)(b * RCH + rc) * D4 + tid] = s;
}

// ---- K2: vmean (LDS) + t = vmean@Wv.T + bv. grid (4,32), 256 thr ----
__global__ void __launch_bounds__(256) k2_mid(const float4* __restrict__ part,
                                              const float4* __restrict__ Wv4,
                                              const float* __restrict__ bv,
                                              float* __restrict__ t) {
    __shared__ float4 vm[D4];
    const int b = blockIdx.x, nch = blockIdx.y, tid = threadIdx.x;

    // finalize mean: thread owns float4 column tid; part[b] is L2-resident
    const float4* p = part + (size_t)b * RCH * D4 + tid;
    float4 s = {0.f, 0.f, 0.f, 0.f};
#pragma unroll 16
    for (int rc = 0; rc < RCH; ++rc) {
        const float4 a = p[rc * D4];
        s.x += a.x; s.y += a.y; s.z += a.z; s.w += a.w;
    }
    const float inv = 1.0f / SEQ;
    s.x *= inv; s.y *= inv; s.z *= inv; s.w *= inv;
    vm[tid] = s;
    __syncthreads();

    const int wave = tid >> 6, lane = tid & 63;
#pragma unroll
    for (int i = 0; i < 8; ++i) {
        const int n = nch * 32 + wave * 8 + i;
        const float4* w = Wv4 + (size_t)n * D4;
        float acc = 0.f;
#pragma unroll
        for (int j = 0; j < 4; ++j) {
            const float4 a  = vm[j * 64 + lane];
            const float4 ww = w[j * 64 + lane];
            acc += a.x * ww.x + a.y * ww.y + a.z * ww.z + a.w * ww.w;
        }
#pragma unroll
        for (int off = 32; off > 0; off >>= 1) acc += __shfl_down(acc, off);
        if (lane == 0) t[b * DIM + n] = acc + bv[n];
    }
}

// ---- K3: r = t@Wo.T + bo. grid 256, 256 thr; wave = one Wo row, all 4 b ----
__global__ void __launch_bounds__(256) k3_matvec(const float4* __restrict__ t4,
                                                 const float4* __restrict__ Wo4,
                                                 const float* __restrict__ bo,
                                                 float* __restrict__ r) {
    __shared__ float4 sh[4 * D4];   // t for all 4 batches, 16 KB
#pragma unroll
    for (int k = 0; k < 4; ++k) sh[k * D4 + threadIdx.x] = t4[k * D4 + threadIdx.x];
    __syncthreads();

    const int wv = threadIdx.x >> 6, lane = threadIdx.x & 63;
    const int n = blockIdx.x * 4 + wv;
    const float4* wrow = Wo4 + (size_t)n * D4;
    float a0 = 0.f, a1 = 0.f, a2 = 0.f, a3 = 0.f;
#pragma unroll
    for (int it = 0; it < 4; ++it) {
        const int col = it * 64 + lane;
        const float4 w  = wrow[col];
        const float4 x0 = sh[col];
        const float4 x1 = sh[D4 + col];
        const float4 x2 = sh[2 * D4 + col];
        const float4 x3 = sh[3 * D4 + col];
        a0 += w.x * x0.x + w.y * x0.y + w.z * x0.z + w.w * x0.w;
        a1 += w.x * x1.x + w.y * x1.y + w.z * x1.z + w.w * x1.w;
        a2 += w.x * x2.x + w.y * x2.y + w.z * x2.z + w.w * x2.w;
        a3 += w.x * x3.x + w.y * x3.y + w.z * x3.z + w.w * x3.w;
    }
#pragma unroll
    for (int off = 32; off > 0; off >>= 1) {
        a0 += __shfl_down(a0, off);
        a1 += __shfl_down(a1, off);
        a2 += __shfl_down(a2, off);
        a3 += __shfl_down(a3, off);
    }
    if (lane == 0) {
        const float bb = bo[n];
        r[0 * DIM + n] = a0 + bb;
        r[1 * DIM + n] = a1 + bb;
        r[2 * DIM + n] = a2 + bb;
        r[3 * DIM + n] = a3 + bb;
    }
}

// ---- K4: broadcast r to out. grid (4,128), 256 thr; block = 8 s-rows ----
__global__ void __launch_bounds__(256) k4_bcast(const float4* __restrict__ r4,
                                                float4* __restrict__ out4) {
    const int b = blockIdx.x, sch = blockIdx.y, tid = threadIdx.x;
    const float4 val = r4[b * D4 + tid];
    float4* o = out4 + (size_t)(b * SEQ + sch * 8) * D4 + tid;
#pragma unroll
    for (int k = 0; k < 8; ++k) o[k * D4] = val;
}

extern "C" void kernel_launch(void* const* d_in, const int* in_sizes, int n_in,
                              void* d_out, int out_size, void* d_ws, size_t ws_size,
                              hipStream_t stream) {
    const float4* v4  = (const float4*)d_in[2];
    const float4* Wv4 = (const float4*)d_in[8];
    const float*  bv  = (const float*)d_in[9];
    const float4* Wo4 = (const float4*)d_in[10];
    const float*  bo  = (const float*)d_in[11];
    float4* out4 = (float4*)d_out;

    float* ws = (float*)d_ws;
    float4* part = (float4*)ws;                       // 4*128*1024 floats = 2 MB
    float*  t    = ws + (size_t)BATCH * RCH * DIM;    // 4096 floats
    float*  r    = t + (size_t)BATCH * DIM;           // 4096 floats

    k1_colsum<<<dim3(BATCH, RCH), 256, 0, stream>>>(v4, part);
    k2_mid<<<dim3(BATCH, 32), 256, 0, stream>>>(part, Wv4, bv, t);
    k3_matvec<<<256, 256, 0, stream>>>((const float4*)t, Wo4, bo, r);
    k4_bcast<<<dim3(BATCH, RCH), 256, 0, stream>>>((const float4*)r, out4);
}

// Round 5
// 21.931 us; speedup vs baseline: 10.5375x; 1.3941x over previous
//
#include <hip/hip_runtime.h>

// Triple softmax along keys == uniform(1/S) to ~1e-7, so
//   out[b,s,:] = ((mean_s' v[b,s',:]) @ Wv.T + bv) @ Wo.T + bo
// independent of q, k, Wq, Wk, padding_mask, s. Measured absmax 2.4e-4
// (threshold 2.34e-3) rounds 1-4.
//
// Round 5: back to R1's ZERO-REDUNDANCY 5-dispatch chain (R2/R4 regressions
// both traced to redundant re-reads of fresh intermediates -> L3 BW).
// Micro-opt each stage: K1 float4+nt (R1 was scalar), K2 32-block LDS tree,
// K3/K4 wave-per-W-row over all 4 batches (W read exactly once), K5 1024-blk
// coalesced nt broadcast.

#define BATCH 4
#define SEQ 1024
#define DIM 1024
#define D4 256            // float4 per row
#define RCH 128           // K1 row-chunks (8 rows each)

typedef float f32x4 __attribute__((ext_vector_type(4)));

// ---- K1: part[b][rc][:] = sum of 8 rows of v. grid (4,128), 256 thr ----
__global__ void __launch_bounds__(256) k1_colsum(const f32x4* __restrict__ v4,
                                                 f32x4* __restrict__ part) {
    const int b = blockIdx.x, rc = blockIdx.y, tid = threadIdx.x;
    const f32x4* p = v4 + (size_t)(b * SEQ + rc * 8) * D4 + tid;
    f32x4 s = {0.f, 0.f, 0.f, 0.f};
#pragma unroll
    for (int i = 0; i < 8; ++i) s += __builtin_nontemporal_load(p + i * D4);
    __builtin_nontemporal_store(s, part + (size_t)(b * RCH + rc) * D4 + tid);
}

// ---- K2: vmean[b][:] = (1/SEQ) * sum_rc part[b][rc][:]. grid 32, 256 thr ----
// block = (b, col-chunk of 32 f4); thread = (col 0..31, group 0..7)
__global__ void __launch_bounds__(256) k2_final(const f32x4* __restrict__ part,
                                                f32x4* __restrict__ vmean) {
    __shared__ f32x4 sh[8][32];
    const int b = blockIdx.x >> 3, cq = blockIdx.x & 7;
    const int col = cq * 32 + (threadIdx.x & 31);
    const int g   = threadIdx.x >> 5;
    const f32x4* p = part + (size_t)(b * RCH + g * 16) * D4 + col;
    f32x4 s = {0.f, 0.f, 0.f, 0.f};
#pragma unroll
    for (int i = 0; i < 16; ++i) s += p[i * D4];
    sh[g][threadIdx.x & 31] = s;
    __syncthreads();
    if (threadIdx.x < 32) {
        f32x4 t = sh[0][threadIdx.x];
#pragma unroll
        for (int j = 1; j < 8; ++j) t += sh[j][threadIdx.x];
        t *= (1.0f / SEQ);
        vmean[(size_t)b * D4 + col] = t;
    }
}

// ---- K3/K4: y[b][n] = bias[n] + x[b]·W[n], wave = one W row, all 4 b ----
// grid 256, 256 thr. Each W byte read exactly once. x (16 KB) staged in LDS.
__global__ void __launch_bounds__(256) k_matvec(const f32x4* __restrict__ x4,
                                                const f32x4* __restrict__ W4,
                                                const float* __restrict__ bias,
                                                float* __restrict__ y) {
    __shared__ f32x4 sh[4 * D4];
#pragma unroll
    for (int k = 0; k < 4; ++k)
        sh[k * D4 + threadIdx.x] = x4[k * D4 + threadIdx.x];
    __syncthreads();

    const int wv = threadIdx.x >> 6, lane = threadIdx.x & 63;
    const int n = blockIdx.x * 4 + wv;
    const f32x4* wrow = W4 + (size_t)n * D4;
    float a0 = 0.f, a1 = 0.f, a2 = 0.f, a3 = 0.f;
#pragma unroll
    for (int it = 0; it < 4; ++it) {
        const int col = it * 64 + lane;
        const f32x4 w  = wrow[col];
        const f32x4 x0 = sh[col];
        const f32x4 x1 = sh[D4 + col];
        const f32x4 x2 = sh[2 * D4 + col];
        const f32x4 x3 = sh[3 * D4 + col];
        a0 += w.x * x0.x + w.y * x0.y + w.z * x0.z + w.w * x0.w;
        a1 += w.x * x1.x + w.y * x1.y + w.z * x1.z + w.w * x1.w;
        a2 += w.x * x2.x + w.y * x2.y + w.z * x2.z + w.w * x2.w;
        a3 += w.x * x3.x + w.y * x3.y + w.z * x3.z + w.w * x3.w;
    }
#pragma unroll
    for (int off = 32; off > 0; off >>= 1) {
        a0 += __shfl_down(a0, off);
        a1 += __shfl_down(a1, off);
        a2 += __shfl_down(a2, off);
        a3 += __shfl_down(a3, off);
    }
    if (lane == 0) {
        const float bb = bias[n];
        y[0 * DIM + n] = a0 + bb;
        y[1 * DIM + n] = a1 + bb;
        y[2 * DIM + n] = a2 + bb;
        y[3 * DIM + n] = a3 + bb;
    }
}

// ---- K5: broadcast r to out. grid (4,256), 256 thr; block = 4 s-rows ----
__global__ void __launch_bounds__(256) k5_bcast(const f32x4* __restrict__ r4,
                                                f32x4* __restrict__ out4) {
    const int b = blockIdx.x, sch = blockIdx.y, tid = threadIdx.x;
    const f32x4 val = r4[(size_t)b * D4 + tid];
    f32x4* o = out4 + (size_t)(b * SEQ + sch * 4) * D4 + tid;
#pragma unroll
    for (int k = 0; k < 4; ++k) __builtin_nontemporal_store(val, o + k * D4);
}

extern "C" void kernel_launch(void* const* d_in, const int* in_sizes, int n_in,
                              void* d_out, int out_size, void* d_ws, size_t ws_size,
                              hipStream_t stream) {
    const f32x4* v4  = (const f32x4*)d_in[2];
    const f32x4* Wv4 = (const f32x4*)d_in[8];
    const float* bv  = (const float*)d_in[9];
    const f32x4* Wo4 = (const f32x4*)d_in[10];
    const float* bo  = (const float*)d_in[11];
    f32x4* out4 = (f32x4*)d_out;

    float* ws = (float*)d_ws;
    f32x4* part  = (f32x4*)ws;                        // 4*128*1024 fl = 2 MB
    float* vmean = ws + (size_t)BATCH * RCH * DIM;    // 4096 floats
    float* t     = vmean + (size_t)BATCH * DIM;       // 4096 floats
    float* r     = t + (size_t)BATCH * DIM;           // 4096 floats

    k1_colsum<<<dim3(BATCH, RCH), 256, 0, stream>>>(v4, part);
    k2_final<<<32, 256, 0, stream>>>(part, (f32x4*)vmean);
    k_matvec<<<256, 256, 0, stream>>>((const f32x4*)vmean, Wv4, bv, t);
    k_matvec<<<256, 256, 0, stream>>>((const f32x4*)t, Wo4, bo, r);
    k5_bcast<<<dim3(BATCH, 256), 256, 0, stream>>>((const f32x4*)r, out4);
}